// Round 11
// baseline (488.507 us; speedup 1.0000x reference)
//
#include <hip/hip_runtime.h>
#include <math.h>

#define NA 8000
#define NV 4000
#define NN 12000
#define NA_PAD 8192
#define NV_PAD 4096
#define KNN_TILE 2048
#define FEAT 32
#define HD 64
#define NLAYER 12
#define E_AA 80000
#define E_AV 120000
#define E_VV 60000
#define E_TOT 260000
#define ENC_SIZE (NV * HD)
#define EPS 1e-5f

__device__ __forceinline__ float wave_sum64(float v) {
#pragma unroll
  for (int off = 1; off < 64; off <<= 1) v += __shfl_xor(v, off);
  return v;
}

// ---------------------------------------------------------------------------
// Pack candidate positions as [x, y, z, |c|^2] float4, padded with cc=+INF.
// ---------------------------------------------------------------------------
__global__ __launch_bounds__(256) void pack_kernel(
    const float* __restrict__ apos, const float* __restrict__ vpos,
    float4* __restrict__ apk, float4* __restrict__ vpk)
{
  const int i = blockIdx.x * 256 + threadIdx.x;
  if (i < NA_PAD) {
    float4 r;
    if (i < NA) {
      const float cx = apos[i*3+0], cy = apos[i*3+1], cz = apos[i*3+2];
      r = make_float4(cx, cy, cz, (cx*cx + cy*cy) + cz*cz);
    } else r = make_float4(0.f, 0.f, 0.f, INFINITY);
    apk[i] = r;
  } else {
    const int j = i - NA_PAD;
    if (j < NV_PAD) {
      float4 r;
      if (j < NV) {
        const float cx = vpos[j*3+0], cy = vpos[j*3+1], cz = vpos[j*3+2];
        r = make_float4(cx, cy, cz, (cx*cx + cy*cy) + cz*cz);
      } else r = make_float4(0.f, 0.f, 0.f, INFINITY);
      vpk[j] = r;
    }
  }
}

// ---------------------------------------------------------------------------
// kNN: ROUND-8 VERBATIM (passing, FROZEN). Per-candidate d2 -> ballot ->
// insert is contraction-stable vs the np reference (6 passing contexts);
// every batched-d2 variant (rounds 4, 9) flipped near-tie selections.
// ---------------------------------------------------------------------------
template<int K, int NC_PAD>
__global__ __launch_bounds__(512) void knn_kernel(
    const float* __restrict__ qpos, const float4* __restrict__ cpk,
    int c_off, int* __restrict__ out_src)
{
  __shared__ float4 tile[KNN_TILE];
  const int tid  = threadIdx.x;
  const int wid  = tid >> 6, lane = tid & 63;
  const int q    = blockIdx.x * 8 + wid;
  const float qx = qpos[q*3+0], qy = qpos[q*3+1], qz = qpos[q*3+2];
  const float qq = (qx*qx + qy*qy) + qz*qz;

  float eD = INFINITY; int eI = 0x7fffffff;   // this lane's entry of the list
  float thrD = INFINITY;                       // K-th best (broadcast)

  for (int t0 = 0; t0 < NC_PAD; t0 += KNN_TILE) {
    __syncthreads();                           // previous tile fully consumed
#pragma unroll
    for (int s = 0; s < KNN_TILE/512; ++s)
      tile[s*512 + tid] = cpk[t0 + s*512 + tid];
    __syncthreads();
#pragma unroll 8
    for (int it = 0; it < KNN_TILE/64; ++it) {
      const int j = t0 + it*64 + lane;
      const float4 c = tile[it*64 + lane];
      const float dot = qx*c.x + qy*c.y + qz*c.z;
      const float d2  = (qq - 2.0f*dot) + c.w;
      unsigned long long m = __ballot(d2 < thrD);
      if (m) {
        do {                                   // wave-uniform insert loop
          const int sl = __ffsll(m) - 1;
          m &= (m - 1ULL);
          const float v  = __shfl(d2, sl);
          const int   vi = j - lane + sl;
          const bool stay = (eD < v) || (eD == v && eI < vi);
          const float pD = __shfl_up(eD, 1);
          const int   pI = __shfl_up(eI, 1);
          int pS = __shfl_up(stay ? 1 : 0, 1);
          if (lane == 0) pS = 1;
          eD = stay ? eD : (pS ? v  : pD);
          eI = stay ? eI : (pS ? vi : pI);
        } while (m);
        thrD = __shfl(eD, K-1);
      }
    }
  }
  if (lane < K) out_src[q*K + lane] = eI + c_off;
}

// ---------------------------------------------------------------------------
// LayerNorm + s/d projection, single-wave version (used by init only).
// ---------------------------------------------------------------------------
__device__ __forceinline__ void ln_sd(
    float v, int node, int lane, int l,
    const float* __restrict__ ln_g, const float* __restrict__ ln_b,
    const float* __restrict__ Ws, const float* __restrict__ Wd,
    float* __restrict__ sbuf, float* __restrict__ dbuf)
{
  const float m = wave_sum64(v) * (1.0f/64.0f);
  const float c = v - m;
  const float var = wave_sum64(c*c) * (1.0f/64.0f);
  const float hn = c * rsqrtf(var + EPS) * ln_g[l*HD + lane] + ln_b[l*HD + lane];
  const float* ws = Ws + (size_t)l*HD*HD;
  const float* wd = Wd + (size_t)l*HD*HD;
  float accs = 0.0f, accd = 0.0f;
#pragma unroll
  for (int j = 0; j < HD; ++j) {
    const float hj = __shfl(hn, j);
    accs += hj * ws[j*HD + lane];
    accd += hj * wd[j*HD + lane];
  }
  sbuf[node*HD + lane] = accs;
  dbuf[node*HD + lane] = accd;
}

// ---------------------------------------------------------------------------
// Fused first kernel: input projection + snapshot0 + LN(0) + s/d projection.
// ---------------------------------------------------------------------------
__global__ __launch_bounds__(64) void init_kernel(
    const float* __restrict__ atom_x, const float* __restrict__ vox_x,
    const float* __restrict__ Wa, const float* __restrict__ ba,
    const float* __restrict__ Wv, const float* __restrict__ bv,
    const float* __restrict__ ln_g, const float* __restrict__ ln_b,
    const float* __restrict__ Ws, const float* __restrict__ Wd,
    float* __restrict__ x, float* __restrict__ snap0,
    float* __restrict__ sbuf, float* __restrict__ dbuf)
{
  const int node = blockIdx.x;
  const int t    = threadIdx.x;
  const float* in; const float* W; const float* b;
  if (node < NA) { in = atom_x + node*FEAT;     W = Wa; b = ba; }
  else           { in = vox_x + (node-NA)*FEAT; W = Wv; b = bv; }
  float acc = b[t];
#pragma unroll
  for (int j = 0; j < FEAT; ++j) acc += in[j] * W[j*HD + t];
  x[node*HD + t] = acc;
  if (node >= NA) snap0[(node-NA)*HD + t] = acc;
  ln_sd(acc, node, t, 0, ln_g, ln_b, Ws, Wd, sbuf, dbuf);
}

// ---------------------------------------------------------------------------
// Edge attribute MLP.
// ---------------------------------------------------------------------------
__device__ __forceinline__ void load_pos(const float* ap, const float* vp,
                                         int i, float& px, float& py, float& pz)
{
  const float* p = (i < NA) ? (ap + i*3) : (vp + (i - NA)*3);
  px = p[0]; py = p[1]; pz = p[2];
}

__global__ __launch_bounds__(256) void edge_attr_kernel(
    const float* __restrict__ atom_pos, const float* __restrict__ vox_pos,
    const int* __restrict__ srcA, const int* __restrict__ srcAV,
    const int* __restrict__ srcVV,
    const float* __restrict__ w1, const float* __restrict__ b1,
    const float* __restrict__ w2, const float* __restrict__ b2,
    float* __restrict__ eattr)
{
  const int e = blockIdx.x * 256 + threadIdx.x;
  if (e >= E_TOT) return;
  int s, d, mi;
  if (e < E_AA)              { mi = 0; s = srcA[e];                 d = e / 10; }
  else if (e < E_AA + E_AV)  { mi = 1; const int t = e - E_AA;      s = srcAV[t]; d = t / 15; }
  else                       { mi = 2; const int t = e - E_AA - E_AV; s = srcVV[t]; d = NA + t / 15; }
  float sx, sy, sz, dx_, dy_, dz_;
  load_pos(atom_pos, vox_pos, s, sx, sy, sz);
  load_pos(atom_pos, vox_pos, d, dx_, dy_, dz_);
  const float ex = sx - dx_, ey = sy - dy_, ez = sz - dz_;
  const float dist = sqrtf(ex*ex + ey*ey + ez*ez);
  float acc = b2[mi];
#pragma unroll
  for (int j = 0; j < 8; ++j) {
    float h = dist * w1[mi*8 + j] + b1[mi*8 + j];
    h = (h > 0.0f) ? h : 0.0f;
    acc += h * w2[mi*8 + j];
  }
  eattr[e] = acc;
}

// ---------------------------------------------------------------------------
// Half-node attention aggregation: wave handles edges [E0, E0+NE) of node n.
// One-pass (srow in registers). Cross-half combine of {max, den, msg} via
// LDS (3 barriers). fmaxf combine exact; den/msg are half-sum reassociations
// (continuous; same class as the j-slice that passed rounds 5-10).
// ---------------------------------------------------------------------------
template<int NE, int E0, bool IS_ATOM>
__device__ __forceinline__ float agg_half(
    int n, int w, int nb, int lane,
    float* __restrict__ x,
    const float* __restrict__ sbuf, const float* __restrict__ dbuf,
    const float* __restrict__ eattr,
    const int* __restrict__ srcA, const int* __restrict__ srcAV,
    const int* __restrict__ srcVV,
    const float* __restrict__ We, const float* __restrict__ att, int l,
    float* __restrict__ snap,
    float (*xch0)[HD], float (*xch1)[HD], float (*xch2)[HD])
{
  const float wet  = We[l*HD + lane];
  const float attv = att[l*HD + lane];
  const float dn   = dbuf[n*HD + lane];
  float srow[NE], escore[NE];
#pragma unroll
  for (int ei = 0; ei < NE; ++ei) {
    const int e = E0 + ei;
    int src, eidx;
    if (IS_ATOM) {
      if (e < 10) { src = srcA[n*10 + e];       eidx = n*10 + e; }
      else        { src = srcAV[n*15 + (e-10)]; eidx = E_AA + n*15 + (e-10); }
    } else {
      const int nv = n - NA;
      src = srcVV[nv*15 + e]; eidx = E_AA + E_AV + nv*15 + e;
    }
    const float sv = sbuf[src*HD + lane];
    srow[ei] = sv;
    float mm = sv + dn + eattr[eidx] * wet;
    mm = (mm >= 0.0f) ? mm : 0.2f * mm;        // leaky_relu(0.2)
    float vv = mm * attv;                       // reduce over d within head
    vv += __shfl_xor(vv, 1); vv += __shfl_xor(vv, 2);
    vv += __shfl_xor(vv, 4); vv += __shfl_xor(vv, 8);
    escore[ei] = vv;
  }
  float mxw = -INFINITY;
#pragma unroll
  for (int ei = 0; ei < NE; ++ei) mxw = fmaxf(mxw, escore[ei]);
  xch0[w][lane] = mxw;
  __syncthreads();
  const float mx = fmaxf(xch0[nb*2][lane], xch0[nb*2+1][lane]);
  float pden = 0.0f;
#pragma unroll
  for (int ei = 0; ei < NE; ++ei) {
    const float a = __expf(escore[ei] - mx);
    escore[ei] = a; pden += a;
  }
  xch1[w][lane] = pden;
  __syncthreads();
  const float den = xch1[nb*2][lane] + xch1[nb*2+1][lane];
  const float inv = 1.0f / den;
  float pmsg = 0.0f;
#pragma unroll
  for (int ei = 0; ei < NE; ++ei) pmsg += (escore[ei] * inv) * srow[ei];
  xch2[w][lane] = pmsg;
  __syncthreads();
  const float msg = xch2[nb*2][lane] + xch2[nb*2+1][lane];
  float xv = x[n*HD + lane] + msg;
  xv = (xv > 0.0f) ? xv : 0.0f;
  if ((w & 1) == 0) {
    x[n*HD + lane] = xv;
    if (!IS_ATOM && snap != nullptr) snap[(n - NA)*HD + lane] = xv;
  }
  return xv;
}

// ---------------------------------------------------------------------------
// Fused layer: 4 nodes/block, 2 waves/node (512 threads). Agg halves the
// serial edge chain; LN(l+1) + s/d projection j-sliced across 8 waves.
// Blocks are node-type homogeneous (NA divisible by 4).
// ---------------------------------------------------------------------------
__global__ __launch_bounds__(512) void layer_kernel(
    float* __restrict__ x,
    const float* __restrict__ sbuf_in, float* __restrict__ dbuf,
    float* __restrict__ sbuf_out,
    const float* __restrict__ eattr,
    const int* __restrict__ srcA, const int* __restrict__ srcAV,
    const int* __restrict__ srcVV,
    const float* __restrict__ We, const float* __restrict__ att,
    const float* __restrict__ ln_g, const float* __restrict__ ln_b,
    const float* __restrict__ Ws, const float* __restrict__ Wd,
    int l, float* __restrict__ snap, int do_next)
{
  const int w = threadIdx.x >> 6, lane = threadIdx.x & 63;
  const int nb = w >> 1;                    // node slot in block (0..3)
  const int n = blockIdx.x * 4 + nb;
  __shared__ float xch0[8][HD], xch1[8][HD], xch2[8][HD];
  __shared__ float hn_sh[4][HD];
  __shared__ float part[8][4][2][HD];

  float xv;
  if (n < NA) {
    if (!do_next) return;                   // whole block returns uniformly
    if ((w & 1) == 0)
      xv = agg_half<13, 0, true>(n, w, nb, lane, x, sbuf_in, dbuf, eattr,
                                 srcA, srcAV, srcVV, We, att, l, nullptr,
                                 xch0, xch1, xch2);
    else
      xv = agg_half<12, 13, true>(n, w, nb, lane, x, sbuf_in, dbuf, eattr,
                                  srcA, srcAV, srcVV, We, att, l, nullptr,
                                  xch0, xch1, xch2);
  } else {
    if ((w & 1) == 0)
      xv = agg_half<8, 0, false>(n, w, nb, lane, x, sbuf_in, dbuf, eattr,
                                 srcA, srcAV, srcVV, We, att, l, snap,
                                 xch0, xch1, xch2);
    else
      xv = agg_half<7, 8, false>(n, w, nb, lane, x, sbuf_in, dbuf, eattr,
                                 srcA, srcAV, srcVV, We, att, l, snap,
                                 xch0, xch1, xch2);
  }
  if (!do_next) return;                     // vox blocks on last layer

  // LayerNorm for layer l+1 (both halves compute identically)
  const int ln = l + 1;
  const float mean = wave_sum64(xv) * (1.0f/64.0f);
  const float cc   = xv - mean;
  const float var  = wave_sum64(cc*cc) * (1.0f/64.0f);
  const float hn   = cc * rsqrtf(var + EPS) * ln_g[ln*HD + lane] + ln_b[ln*HD + lane];
  if ((w & 1) == 0) hn_sh[nb][lane] = hn;
  __syncthreads();

  // j-sliced projection: wave w covers j in [w*8, w*8+8) for 4 nodes
  const float* wsp = Ws + (size_t)ln*HD*HD;
  const float* wdp = Wd + (size_t)ln*HD*HD;
  float as0=0.f, as1=0.f, as2=0.f, as3=0.f;
  float ad0=0.f, ad1=0.f, ad2=0.f, ad3=0.f;
#pragma unroll
  for (int jj = 0; jj < 8; ++jj) {
    const int j = w*8 + jj;
    const float wvs = wsp[j*HD + lane];
    const float wvd = wdp[j*HD + lane];
    const float h0 = hn_sh[0][j], h1 = hn_sh[1][j];
    const float h2 = hn_sh[2][j], h3 = hn_sh[3][j];
    as0 += h0*wvs; ad0 += h0*wvd;
    as1 += h1*wvs; ad1 += h1*wvd;
    as2 += h2*wvs; ad2 += h2*wvd;
    as3 += h3*wvs; ad3 += h3*wvd;
  }
  part[w][0][0][lane] = as0; part[w][0][1][lane] = ad0;
  part[w][1][0][lane] = as1; part[w][1][1][lane] = ad1;
  part[w][2][0][lane] = as2; part[w][2][1][lane] = ad2;
  part[w][3][0][lane] = as3; part[w][3][1][lane] = ad3;
  __syncthreads();

  if ((w & 1) == 0) {
    const float accs = (((part[0][nb][0][lane] + part[1][nb][0][lane])
                       + (part[2][nb][0][lane] + part[3][nb][0][lane]))
                      + ((part[4][nb][0][lane] + part[5][nb][0][lane])
                       + (part[6][nb][0][lane] + part[7][nb][0][lane])));
    sbuf_out[n*HD + lane] = accs;
  } else {
    const float accd = (((part[0][nb][1][lane] + part[1][nb][1][lane])
                       + (part[2][nb][1][lane] + part[3][nb][1][lane]))
                      + ((part[4][nb][1][lane] + part[5][nb][1][lane])
                       + (part[6][nb][1][lane] + part[7][nb][1][lane])));
    dbuf[n*HD + lane] = accd;
  }
}

// ---------------------------------------------------------------------------
// Output head: 4 vox nodes/block, j-sliced matmuls amortize weight loads 4x.
// ---------------------------------------------------------------------------
__global__ __launch_bounds__(256) void head_kernel(
    const float* __restrict__ snaps,
    const float* __restrict__ Wo1, const float* __restrict__ bo1,
    const float* __restrict__ Wo2, const float* __restrict__ bo2,
    float* __restrict__ out)
{
  const int wid = threadIdx.x >> 6, lane = threadIdx.x & 63;
  const int n = blockIdx.x * 4 + wid;
  __shared__ float cat[4][7*HD];
  __shared__ float part[4][4][HD];
  __shared__ float o1[4][HD];

#pragma unroll
  for (int c = 0; c < 7; ++c)
    cat[wid][c*HD + lane] = snaps[(size_t)c*NV*HD + n*HD + lane];
  __syncthreads();

  float a0=0.f, a1=0.f, a2=0.f, a3=0.f;
  for (int jj = 0; jj < 112; ++jj) {
    const int j = wid*112 + jj;
    const float w = Wo1[j*HD + lane];
    a0 += cat[0][j]*w; a1 += cat[1][j]*w;
    a2 += cat[2][j]*w; a3 += cat[3][j]*w;
  }
  part[wid][0][lane] = a0; part[wid][1][lane] = a1;
  part[wid][2][lane] = a2; part[wid][3][lane] = a3;
  __syncthreads();

  float acc = bo1[lane] + ((part[0][wid][lane] + part[1][wid][lane])
                         + (part[2][wid][lane] + part[3][wid][lane]));
  acc = fmaxf(acc, 0.0f);
  o1[wid][lane] = acc;
  __syncthreads();

  float b0=0.f, b1=0.f, b2=0.f, b3=0.f;
#pragma unroll
  for (int jj = 0; jj < 16; ++jj) {
    const int j = wid*16 + jj;
    const float w = Wo2[j*HD + lane];
    b0 += o1[0][j]*w; b1 += o1[1][j]*w;
    b2 += o1[2][j]*w; b3 += o1[3][j]*w;
  }
  __syncthreads();                       // part reuse
  part[wid][0][lane] = b0; part[wid][1][lane] = b1;
  part[wid][2][lane] = b2; part[wid][3][lane] = b3;
  __syncthreads();

  const float acc2 = bo2[lane] + ((part[0][wid][lane] + part[1][wid][lane])
                                + (part[2][wid][lane] + part[3][wid][lane]));
  out[n*HD + lane] = acc2;
}

__global__ __launch_bounds__(256) void copy_pos_kernel(
    const float* __restrict__ vp, float* __restrict__ out)
{
  const int i = blockIdx.x * 256 + threadIdx.x;
  if (i < NV*3) out[ENC_SIZE + i] = vp[i];
}

// ---------------------------------------------------------------------------
extern "C" void kernel_launch(void* const* d_in, const int* in_sizes, int n_in,
                              void* d_out, int out_size, void* d_ws, size_t ws_size,
                              hipStream_t stream)
{
  const float* atom_x    = (const float*)d_in[0];
  const float* atom_pos  = (const float*)d_in[1];
  const float* vox_x     = (const float*)d_in[2];
  const float* vox_pos   = (const float*)d_in[3];
  const float* W_atom_in = (const float*)d_in[4];
  const float* b_atom_in = (const float*)d_in[5];
  const float* W_vox_in  = (const float*)d_in[6];
  const float* b_vox_in  = (const float*)d_in[7];
  const float* emlp_w1   = (const float*)d_in[8];
  const float* emlp_b1   = (const float*)d_in[9];
  const float* emlp_w2   = (const float*)d_in[10];
  const float* emlp_b2   = (const float*)d_in[11];
  const float* ln_g      = (const float*)d_in[12];
  const float* ln_b      = (const float*)d_in[13];
  const float* Ws        = (const float*)d_in[14];
  const float* Wd        = (const float*)d_in[15];
  const float* We        = (const float*)d_in[16];
  const float* att       = (const float*)d_in[17];
  const float* Wo1       = (const float*)d_in[18];
  const float* bo1       = (const float*)d_in[19];
  const float* Wo2       = (const float*)d_in[20];
  const float* bo2       = (const float*)d_in[21];
  float* out = (float*)d_out;

  // workspace layout (floats), ~21.8 MB
  float* ws    = (float*)d_ws;
  float* x     = ws;                          // [NN][HD]
  float* sA    = x  + (size_t)NN*HD;          // [NN][HD] sbuf ping
  float* sB    = sA + (size_t)NN*HD;          // [NN][HD] sbuf pong
  float* dbuf  = sB + (size_t)NN*HD;          // [NN][HD]
  float* eattr = dbuf + (size_t)NN*HD;        // [E_TOT]
  float* snaps = eattr + E_TOT;               // [7][NV][HD]
  int*   srcA  = (int*)(snaps + (size_t)7*NV*HD);
  int*   srcAV = srcA  + E_AA;
  int*   srcVV = srcAV + E_AV;
  float4* apk  = (float4*)(srcVV + E_VV);     // [NA_PAD] packed atoms
  float4* vpk  = apk + NA_PAD;                // [NV_PAD] packed voxels

  // 1. pack candidates, then kNN graphs (8 queries/block, 1 wave/query)
  pack_kernel<<<(NA_PAD + NV_PAD + 255)/256, 256, 0, stream>>>(
      atom_pos, vox_pos, apk, vpk);
  knn_kernel<10, NA_PAD><<<NA/8, 512, 0, stream>>>(atom_pos, apk, 0,  srcA);
  knn_kernel<15, NV_PAD><<<NA/8, 512, 0, stream>>>(atom_pos, vpk, NA, srcAV);
  knn_kernel<15, NV_PAD><<<NV/8, 512, 0, stream>>>(vox_pos,  vpk, NA, srcVV);
  // 2. edge attributes
  edge_attr_kernel<<<(E_TOT + 255)/256, 256, 0, stream>>>(
      atom_pos, vox_pos, srcA, srcAV, srcVV,
      emlp_w1, emlp_b1, emlp_w2, emlp_b2, eattr);
  // 3. fused input proj + LN0 + s/d proj
  init_kernel<<<NN, 64, 0, stream>>>(atom_x, vox_x, W_atom_in, b_atom_in,
                                     W_vox_in, b_vox_in, ln_g, ln_b, Ws, Wd,
                                     x, snaps, sA, dbuf);
  // 4. 12 fused GAT layers (4 nodes/block, 2 waves/node)
  for (int l = 0; l < NLAYER; ++l) {
    float* s_in  = (l & 1) ? sB : sA;
    float* s_out = (l & 1) ? sA : sB;
    float* snap  = (l & 1) ? (snaps + (size_t)(l/2 + 1)*NV*HD) : nullptr;
    layer_kernel<<<NN/4, 512, 0, stream>>>(x, s_in, dbuf, s_out, eattr,
                                           srcA, srcAV, srcVV, We, att,
                                           ln_g, ln_b, Ws, Wd, l, snap,
                                           (l < NLAYER-1) ? 1 : 0);
  }
  // 5. output head + vox_pos passthrough
  head_kernel<<<NV/4, 256, 0, stream>>>(snaps, Wo1, bo1, Wo2, bo2, out);
  copy_pos_kernel<<<(NV*3 + 255)/256, 256, 0, stream>>>(vox_pos, out);
}

// Round 12
// 463.154 us; speedup vs baseline: 1.0547x; 1.0547x over previous
//
#include <hip/hip_runtime.h>
#include <math.h>

#define NA 8000
#define NV 4000
#define NN 12000
#define NA_PAD 8192
#define NV_PAD 4096
#define KNN_TILE 2048
#define FEAT 32
#define HD 64
#define NLAYER 12
#define E_AA 80000
#define E_AV 120000
#define E_VV 60000
#define E_TOT 260000
#define ENC_SIZE (NV * HD)
#define EPS 1e-5f

__device__ __forceinline__ float wave_sum64(float v) {
#pragma unroll
  for (int off = 1; off < 64; off <<= 1) v += __shfl_xor(v, off);
  return v;
}

// ---------------------------------------------------------------------------
// Pack candidate positions as [x, y, z, |c|^2] float4, padded with cc=+INF.
// ---------------------------------------------------------------------------
__global__ __launch_bounds__(256) void pack_kernel(
    const float* __restrict__ apos, const float* __restrict__ vpos,
    float4* __restrict__ apk, float4* __restrict__ vpk)
{
  const int i = blockIdx.x * 256 + threadIdx.x;
  if (i < NA_PAD) {
    float4 r;
    if (i < NA) {
      const float cx = apos[i*3+0], cy = apos[i*3+1], cz = apos[i*3+2];
      r = make_float4(cx, cy, cz, (cx*cx + cy*cy) + cz*cz);
    } else r = make_float4(0.f, 0.f, 0.f, INFINITY);
    apk[i] = r;
  } else {
    const int j = i - NA_PAD;
    if (j < NV_PAD) {
      float4 r;
      if (j < NV) {
        const float cx = vpos[j*3+0], cy = vpos[j*3+1], cz = vpos[j*3+2];
        r = make_float4(cx, cy, cz, (cx*cx + cy*cy) + cz*cz);
      } else r = make_float4(0.f, 0.f, 0.f, INFINITY);
      vpk[j] = r;
    }
  }
}

// ---------------------------------------------------------------------------
// kNN: ROUND-8 VERBATIM (passing, FROZEN). Per-candidate d2 -> ballot ->
// insert is contraction-stable vs the np reference (6 passing contexts);
// every batched-d2 variant (rounds 4, 9) flipped near-tie selections.
// ---------------------------------------------------------------------------
template<int K, int NC_PAD>
__global__ __launch_bounds__(512) void knn_kernel(
    const float* __restrict__ qpos, const float4* __restrict__ cpk,
    int c_off, int* __restrict__ out_src)
{
  __shared__ float4 tile[KNN_TILE];
  const int tid  = threadIdx.x;
  const int wid  = tid >> 6, lane = tid & 63;
  const int q    = blockIdx.x * 8 + wid;
  const float qx = qpos[q*3+0], qy = qpos[q*3+1], qz = qpos[q*3+2];
  const float qq = (qx*qx + qy*qy) + qz*qz;

  float eD = INFINITY; int eI = 0x7fffffff;   // this lane's entry of the list
  float thrD = INFINITY;                       // K-th best (broadcast)

  for (int t0 = 0; t0 < NC_PAD; t0 += KNN_TILE) {
    __syncthreads();                           // previous tile fully consumed
#pragma unroll
    for (int s = 0; s < KNN_TILE/512; ++s)
      tile[s*512 + tid] = cpk[t0 + s*512 + tid];
    __syncthreads();
#pragma unroll 8
    for (int it = 0; it < KNN_TILE/64; ++it) {
      const int j = t0 + it*64 + lane;
      const float4 c = tile[it*64 + lane];
      const float dot = qx*c.x + qy*c.y + qz*c.z;
      const float d2  = (qq - 2.0f*dot) + c.w;
      unsigned long long m = __ballot(d2 < thrD);
      if (m) {
        do {                                   // wave-uniform insert loop
          const int sl = __ffsll(m) - 1;
          m &= (m - 1ULL);
          const float v  = __shfl(d2, sl);
          const int   vi = j - lane + sl;
          const bool stay = (eD < v) || (eD == v && eI < vi);
          const float pD = __shfl_up(eD, 1);
          const int   pI = __shfl_up(eI, 1);
          int pS = __shfl_up(stay ? 1 : 0, 1);
          if (lane == 0) pS = 1;
          eD = stay ? eD : (pS ? v  : pD);
          eI = stay ? eI : (pS ? vi : pI);
        } while (m);
        thrD = __shfl(eD, K-1);
      }
    }
  }
  if (lane < K) out_src[q*K + lane] = eI + c_off;
}

// ---------------------------------------------------------------------------
// LayerNorm + s/d projection, single-wave version (used by init only).
// ---------------------------------------------------------------------------
__device__ __forceinline__ void ln_sd(
    float v, int node, int lane, int l,
    const float* __restrict__ ln_g, const float* __restrict__ ln_b,
    const float* __restrict__ Ws, const float* __restrict__ Wd,
    float* __restrict__ sbuf, float* __restrict__ dbuf)
{
  const float m = wave_sum64(v) * (1.0f/64.0f);
  const float c = v - m;
  const float var = wave_sum64(c*c) * (1.0f/64.0f);
  const float hn = c * rsqrtf(var + EPS) * ln_g[l*HD + lane] + ln_b[l*HD + lane];
  const float* ws = Ws + (size_t)l*HD*HD;
  const float* wd = Wd + (size_t)l*HD*HD;
  float accs = 0.0f, accd = 0.0f;
#pragma unroll
  for (int j = 0; j < HD; ++j) {
    const float hj = __shfl(hn, j);
    accs += hj * ws[j*HD + lane];
    accd += hj * wd[j*HD + lane];
  }
  sbuf[node*HD + lane] = accs;
  dbuf[node*HD + lane] = accd;
}

// ---------------------------------------------------------------------------
// Fused first kernel: input projection + snapshot0 + LN(0) + s/d projection.
// ---------------------------------------------------------------------------
__global__ __launch_bounds__(64) void init_kernel(
    const float* __restrict__ atom_x, const float* __restrict__ vox_x,
    const float* __restrict__ Wa, const float* __restrict__ ba,
    const float* __restrict__ Wv, const float* __restrict__ bv,
    const float* __restrict__ ln_g, const float* __restrict__ ln_b,
    const float* __restrict__ Ws, const float* __restrict__ Wd,
    float* __restrict__ x, float* __restrict__ snap0,
    float* __restrict__ sbuf, float* __restrict__ dbuf)
{
  const int node = blockIdx.x;
  const int t    = threadIdx.x;
  const float* in; const float* W; const float* b;
  if (node < NA) { in = atom_x + node*FEAT;     W = Wa; b = ba; }
  else           { in = vox_x + (node-NA)*FEAT; W = Wv; b = bv; }
  float acc = b[t];
#pragma unroll
  for (int j = 0; j < FEAT; ++j) acc += in[j] * W[j*HD + t];
  x[node*HD + t] = acc;
  if (node >= NA) snap0[(node-NA)*HD + t] = acc;
  ln_sd(acc, node, t, 0, ln_g, ln_b, Ws, Wd, sbuf, dbuf);
}

// ---------------------------------------------------------------------------
// Edge attribute MLP.
// ---------------------------------------------------------------------------
__device__ __forceinline__ void load_pos(const float* ap, const float* vp,
                                         int i, float& px, float& py, float& pz)
{
  const float* p = (i < NA) ? (ap + i*3) : (vp + (i - NA)*3);
  px = p[0]; py = p[1]; pz = p[2];
}

__global__ __launch_bounds__(256) void edge_attr_kernel(
    const float* __restrict__ atom_pos, const float* __restrict__ vox_pos,
    const int* __restrict__ srcA, const int* __restrict__ srcAV,
    const int* __restrict__ srcVV,
    const float* __restrict__ w1, const float* __restrict__ b1,
    const float* __restrict__ w2, const float* __restrict__ b2,
    float* __restrict__ eattr)
{
  const int e = blockIdx.x * 256 + threadIdx.x;
  if (e >= E_TOT) return;
  int s, d, mi;
  if (e < E_AA)              { mi = 0; s = srcA[e];                 d = e / 10; }
  else if (e < E_AA + E_AV)  { mi = 1; const int t = e - E_AA;      s = srcAV[t]; d = t / 15; }
  else                       { mi = 2; const int t = e - E_AA - E_AV; s = srcVV[t]; d = NA + t / 15; }
  float sx, sy, sz, dx_, dy_, dz_;
  load_pos(atom_pos, vox_pos, s, sx, sy, sz);
  load_pos(atom_pos, vox_pos, d, dx_, dy_, dz_);
  const float ex = sx - dx_, ey = sy - dy_, ez = sz - dz_;
  const float dist = sqrtf(ex*ex + ey*ey + ez*ez);
  float acc = b2[mi];
#pragma unroll
  for (int j = 0; j < 8; ++j) {
    float h = dist * w1[mi*8 + j] + b1[mi*8 + j];
    h = (h > 0.0f) ? h : 0.0f;
    acc += h * w2[mi*8 + j];
  }
  eattr[e] = acc;
}

// ---------------------------------------------------------------------------
// Per-node attention aggregation, PHASE-SEPARATED (one wave per node):
//  phase 0: batch-load src indices + eattr (sequential, 1-2 lines)
//  phase 1: batch-issue all NE row gathers (straight-line, no convergent ops
//           between loads -> compiler hoists; ONE latency shot, not NE)
//  phase 2: scores (arithmetic bit-identical to the passing round-10 pass-1)
//  phase 3: softmax + msg from registers (srow reused, no re-gather)
// ---------------------------------------------------------------------------
template<int NE, bool IS_ATOM>
__device__ __forceinline__ float agg_node(
    int n, int lane,
    float* __restrict__ x,
    const float* __restrict__ sbuf, const float* __restrict__ dbuf,
    const float* __restrict__ eattr,
    const int* __restrict__ srcA, const int* __restrict__ srcAV,
    const int* __restrict__ srcVV,
    const float* __restrict__ We, const float* __restrict__ att, int l,
    float* __restrict__ snap)
{
  const float wet  = We[l*HD + lane];
  const float attv = att[l*HD + lane];
  const float dn   = dbuf[n*HD + lane];

  int esrc[NE]; float eat[NE];
#pragma unroll
  for (int e = 0; e < NE; ++e) {
    int src, eidx;
    if (IS_ATOM) {
      if (e < 10) { src = srcA[n*10 + e];       eidx = n*10 + e; }
      else        { src = srcAV[n*15 + (e-10)]; eidx = E_AA + n*15 + (e-10); }
    } else {
      const int nv = n - NA;
      src = srcVV[nv*15 + e]; eidx = E_AA + E_AV + nv*15 + e;
    }
    esrc[e] = src;
    eat[e]  = eattr[eidx];
  }

  float srow[NE];
#pragma unroll
  for (int e = 0; e < NE; ++e) srow[e] = sbuf[esrc[e]*HD + lane];

  float escore[NE];
#pragma unroll
  for (int e = 0; e < NE; ++e) {
    float mm = srow[e] + dn + eat[e] * wet;
    mm = (mm >= 0.0f) ? mm : 0.2f * mm;        // leaky_relu(0.2)
    float vv = mm * attv;                       // reduce over d within head
    vv += __shfl_xor(vv, 1); vv += __shfl_xor(vv, 2);
    vv += __shfl_xor(vv, 4); vv += __shfl_xor(vv, 8);
    escore[e] = vv;
  }
  float mx = -INFINITY;
#pragma unroll
  for (int e = 0; e < NE; ++e) mx = fmaxf(mx, escore[e]);
  float den = 0.0f;
#pragma unroll
  for (int e = 0; e < NE; ++e) {
    const float a = __expf(escore[e] - mx);
    escore[e] = a; den += a;
  }
  const float inv = 1.0f / den;
  float msg = 0.0f;
#pragma unroll
  for (int e = 0; e < NE; ++e) msg += (escore[e] * inv) * srow[e];
  float xv = x[n*HD + lane] + msg;
  xv = (xv > 0.0f) ? xv : 0.0f;
  x[n*HD + lane] = xv;
  if (!IS_ATOM && snap != nullptr) snap[(n - NA)*HD + lane] = xv;
  return xv;
}

// ---------------------------------------------------------------------------
// Fused layer (ROUND-10 structure): 4 nodes/block (one wave each) agg, then
// LN(l+1) + s/d proj j-sliced across the block's 4 waves (4x weight reuse).
// ---------------------------------------------------------------------------
__global__ __launch_bounds__(256) void layer_kernel(
    float* __restrict__ x,
    const float* __restrict__ sbuf_in, float* __restrict__ dbuf,
    float* __restrict__ sbuf_out,
    const float* __restrict__ eattr,
    const int* __restrict__ srcA, const int* __restrict__ srcAV,
    const int* __restrict__ srcVV,
    const float* __restrict__ We, const float* __restrict__ att,
    const float* __restrict__ ln_g, const float* __restrict__ ln_b,
    const float* __restrict__ Ws, const float* __restrict__ Wd,
    int l, float* __restrict__ snap, int do_next)
{
  const int wid = threadIdx.x >> 6, lane = threadIdx.x & 63;
  const int n = blockIdx.x * 4 + wid;       // blocks are node-type homogeneous
  __shared__ float hn_sh[4][HD];
  __shared__ float part[4][4][2][HD];

  float xv;
  if (n < NA) {
    if (!do_next) return;                    // whole block returns uniformly
    xv = agg_node<25,true>(n, lane, x, sbuf_in, dbuf, eattr,
                           srcA, srcAV, srcVV, We, att, l, nullptr);
  } else {
    xv = agg_node<15,false>(n, lane, x, sbuf_in, dbuf, eattr,
                            srcA, srcAV, srcVV, We, att, l, snap);
  }
  if (!do_next) return;

  // LayerNorm for layer l+1 (per-wave, same arithmetic as before)
  const int ln = l + 1;
  const float mean = wave_sum64(xv) * (1.0f/64.0f);
  const float cc   = xv - mean;
  const float var  = wave_sum64(cc*cc) * (1.0f/64.0f);
  const float hn   = cc * rsqrtf(var + EPS) * ln_g[ln*HD + lane] + ln_b[ln*HD + lane];
  hn_sh[wid][lane] = hn;
  __syncthreads();

  // j-sliced projection: wave wid covers j in [wid*16, wid*16+16) for 4 nodes
  const float* wsp = Ws + (size_t)ln*HD*HD;
  const float* wdp = Wd + (size_t)ln*HD*HD;
  float as0=0.f, as1=0.f, as2=0.f, as3=0.f;
  float ad0=0.f, ad1=0.f, ad2=0.f, ad3=0.f;
#pragma unroll
  for (int jj = 0; jj < 16; ++jj) {
    const int j = wid*16 + jj;
    const float wvs = wsp[j*HD + lane];
    const float wvd = wdp[j*HD + lane];
    const float h0 = hn_sh[0][j], h1 = hn_sh[1][j];
    const float h2 = hn_sh[2][j], h3 = hn_sh[3][j];
    as0 += h0*wvs; ad0 += h0*wvd;
    as1 += h1*wvs; ad1 += h1*wvd;
    as2 += h2*wvs; ad2 += h2*wvd;
    as3 += h3*wvs; ad3 += h3*wvd;
  }
  part[wid][0][0][lane] = as0; part[wid][0][1][lane] = ad0;
  part[wid][1][0][lane] = as1; part[wid][1][1][lane] = ad1;
  part[wid][2][0][lane] = as2; part[wid][2][1][lane] = ad2;
  part[wid][3][0][lane] = as3; part[wid][3][1][lane] = ad3;
  __syncthreads();

  const float accs = ((part[0][wid][0][lane] + part[1][wid][0][lane])
                    + (part[2][wid][0][lane] + part[3][wid][0][lane]));
  const float accd = ((part[0][wid][1][lane] + part[1][wid][1][lane])
                    + (part[2][wid][1][lane] + part[3][wid][1][lane]));
  sbuf_out[n*HD + lane] = accs;
  dbuf[n*HD + lane]     = accd;
}

// ---------------------------------------------------------------------------
// Output head: 4 vox nodes/block, j-sliced matmuls amortize weight loads 4x.
// ---------------------------------------------------------------------------
__global__ __launch_bounds__(256) void head_kernel(
    const float* __restrict__ snaps,
    const float* __restrict__ Wo1, const float* __restrict__ bo1,
    const float* __restrict__ Wo2, const float* __restrict__ bo2,
    float* __restrict__ out)
{
  const int wid = threadIdx.x >> 6, lane = threadIdx.x & 63;
  const int n = blockIdx.x * 4 + wid;
  __shared__ float cat[4][7*HD];
  __shared__ float part[4][4][HD];
  __shared__ float o1[4][HD];

#pragma unroll
  for (int c = 0; c < 7; ++c)
    cat[wid][c*HD + lane] = snaps[(size_t)c*NV*HD + n*HD + lane];
  __syncthreads();

  float a0=0.f, a1=0.f, a2=0.f, a3=0.f;
  for (int jj = 0; jj < 112; ++jj) {
    const int j = wid*112 + jj;
    const float w = Wo1[j*HD + lane];
    a0 += cat[0][j]*w; a1 += cat[1][j]*w;
    a2 += cat[2][j]*w; a3 += cat[3][j]*w;
  }
  part[wid][0][lane] = a0; part[wid][1][lane] = a1;
  part[wid][2][lane] = a2; part[wid][3][lane] = a3;
  __syncthreads();

  float acc = bo1[lane] + ((part[0][wid][lane] + part[1][wid][lane])
                         + (part[2][wid][lane] + part[3][wid][lane]));
  acc = fmaxf(acc, 0.0f);
  o1[wid][lane] = acc;
  __syncthreads();

  float b0=0.f, b1=0.f, b2=0.f, b3=0.f;
#pragma unroll
  for (int jj = 0; jj < 16; ++jj) {
    const int j = wid*16 + jj;
    const float w = Wo2[j*HD + lane];
    b0 += o1[0][j]*w; b1 += o1[1][j]*w;
    b2 += o1[2][j]*w; b3 += o1[3][j]*w;
  }
  __syncthreads();                       // part reuse
  part[wid][0][lane] = b0; part[wid][1][lane] = b1;
  part[wid][2][lane] = b2; part[wid][3][lane] = b3;
  __syncthreads();

  const float acc2 = bo2[lane] + ((part[0][wid][lane] + part[1][wid][lane])
                                + (part[2][wid][lane] + part[3][wid][lane]));
  out[n*HD + lane] = acc2;
}

__global__ __launch_bounds__(256) void copy_pos_kernel(
    const float* __restrict__ vp, float* __restrict__ out)
{
  const int i = blockIdx.x * 256 + threadIdx.x;
  if (i < NV*3) out[ENC_SIZE + i] = vp[i];
}

// ---------------------------------------------------------------------------
extern "C" void kernel_launch(void* const* d_in, const int* in_sizes, int n_in,
                              void* d_out, int out_size, void* d_ws, size_t ws_size,
                              hipStream_t stream)
{
  const float* atom_x    = (const float*)d_in[0];
  const float* atom_pos  = (const float*)d_in[1];
  const float* vox_x     = (const float*)d_in[2];
  const float* vox_pos   = (const float*)d_in[3];
  const float* W_atom_in = (const float*)d_in[4];
  const float* b_atom_in = (const float*)d_in[5];
  const float* W_vox_in  = (const float*)d_in[6];
  const float* b_vox_in  = (const float*)d_in[7];
  const float* emlp_w1   = (const float*)d_in[8];
  const float* emlp_b1   = (const float*)d_in[9];
  const float* emlp_w2   = (const float*)d_in[10];
  const float* emlp_b2   = (const float*)d_in[11];
  const float* ln_g      = (const float*)d_in[12];
  const float* ln_b      = (const float*)d_in[13];
  const float* Ws        = (const float*)d_in[14];
  const float* Wd        = (const float*)d_in[15];
  const float* We        = (const float*)d_in[16];
  const float* att       = (const float*)d_in[17];
  const float* Wo1       = (const float*)d_in[18];
  const float* bo1       = (const float*)d_in[19];
  const float* Wo2       = (const float*)d_in[20];
  const float* bo2       = (const float*)d_in[21];
  float* out = (float*)d_out;

  // workspace layout (floats), ~21.8 MB
  float* ws    = (float*)d_ws;
  float* x     = ws;                          // [NN][HD]
  float* sA    = x  + (size_t)NN*HD;          // [NN][HD] sbuf ping
  float* sB    = sA + (size_t)NN*HD;          // [NN][HD] sbuf pong
  float* dbuf  = sB + (size_t)NN*HD;          // [NN][HD]
  float* eattr = dbuf + (size_t)NN*HD;        // [E_TOT]
  float* snaps = eattr + E_TOT;               // [7][NV][HD]
  int*   srcA  = (int*)(snaps + (size_t)7*NV*HD);
  int*   srcAV = srcA  + E_AA;
  int*   srcVV = srcAV + E_AV;
  float4* apk  = (float4*)(srcVV + E_VV);     // [NA_PAD] packed atoms
  float4* vpk  = apk + NA_PAD;                // [NV_PAD] packed voxels

  // 1. pack candidates, then kNN graphs (8 queries/block, 1 wave/query)
  pack_kernel<<<(NA_PAD + NV_PAD + 255)/256, 256, 0, stream>>>(
      atom_pos, vox_pos, apk, vpk);
  knn_kernel<10, NA_PAD><<<NA/8, 512, 0, stream>>>(atom_pos, apk, 0,  srcA);
  knn_kernel<15, NV_PAD><<<NA/8, 512, 0, stream>>>(atom_pos, vpk, NA, srcAV);
  knn_kernel<15, NV_PAD><<<NV/8, 512, 0, stream>>>(vox_pos,  vpk, NA, srcVV);
  // 2. edge attributes
  edge_attr_kernel<<<(E_TOT + 255)/256, 256, 0, stream>>>(
      atom_pos, vox_pos, srcA, srcAV, srcVV,
      emlp_w1, emlp_b1, emlp_w2, emlp_b2, eattr);
  // 3. fused input proj + LN0 + s/d proj
  init_kernel<<<NN, 64, 0, stream>>>(atom_x, vox_x, W_atom_in, b_atom_in,
                                     W_vox_in, b_vox_in, ln_g, ln_b, Ws, Wd,
                                     x, snaps, sA, dbuf);
  // 4. 12 fused GAT layers (4 nodes/block; blocks are type-homogeneous)
  for (int l = 0; l < NLAYER; ++l) {
    float* s_in  = (l & 1) ? sB : sA;
    float* s_out = (l & 1) ? sA : sB;
    float* snap  = (l & 1) ? (snaps + (size_t)(l/2 + 1)*NV*HD) : nullptr;
    layer_kernel<<<NN/4, 256, 0, stream>>>(x, s_in, dbuf, s_out, eattr,
                                           srcA, srcAV, srcVV, We, att,
                                           ln_g, ln_b, Ws, Wd, l, snap,
                                           (l < NLAYER-1) ? 1 : 0);
  }
  // 5. output head + vox_pos passthrough
  head_kernel<<<NV/4, 256, 0, stream>>>(snaps, Wo1, bo1, Wo2, bo2, out);
  copy_pos_kernel<<<(NV*3 + 255)/256, 256, 0, stream>>>(vox_pos, out);
}